// Round 12
// baseline (306.473 us; speedup 1.0000x reference)
//
#include <hip/hip_runtime.h>

#define BATCH 64
#define MM 512
#define NN 512
#define DDIM 64

#define K2E   14.426950408889634f     // log2(e)/gamma, gamma=0.1
#define GLN2  0.06931471805599453f    // gamma*ln(2)
#define NEGB  (-1.4426950e11f)        // t-domain encoding of R=BIG=1e10

typedef __attribute__((ext_vector_type(8))) short short8;    // 8 bf16 (4 VGPR)
typedef __attribute__((ext_vector_type(4))) float floatx4;   // MFMA acc

// ---------------------------------------------------------------------------
// Kernel 1 (MFMA): t-domain D' = min(0, 2*K2E*G - K2E|x|^2 - K2E|y|^2) where
// G = x.y via bf16 hi/lo split (hh + hl + lh). R8 structure verbatim; the
// ONLY change vs R8 is the staging conversion: truncation-based hi/lo split
// (hi = f & 0xFFFF0000, lo = trunc-bf16(f - hi)) packed with shift+or —
// ~half the VALU of the software-RNE version. P layout (row-major chunk
// interior) and everything downstream identical to R8.
// P[b][tg=i>>3][m=j>>2][r=i&7][c=j&3].
// ---------------------------------------------------------------------------
#define LDSTRU 36   // uints per LDS row (72 bf16 = 64 + 8 pad; 144 B)
__global__ __launch_bounds__(256) void compute_d_kernel(const float* __restrict__ x,
                                                        const float* __restrict__ y,
                                                        float* __restrict__ P) {
    __shared__ unsigned int xhiW[128 * LDSTRU], xloW[128 * LDSTRU];
    __shared__ unsigned int yhiW[128 * LDSTRU], yloW[128 * LDSTRU];
    __shared__ float xnk[128], ynk[128];

    const int b  = blockIdx.z;
    const int i0 = blockIdx.y * 128;
    const int j0 = blockIdx.x * 128;
    const int tid = threadIdx.x;

    const float* xb = x + ((size_t)b * MM + i0) * DDIM;
    const float* yb = y + ((size_t)b * NN + j0) * DDIM;

    // ---- stage + convert to hi/lo bf16 via truncation split ----
#pragma unroll
    for (int it = 0; it < 8; ++it) {
        int idx = it * 256 + tid;        // 0..2047 float4-chunks
        int row = idx & 127;
        int k4  = idx >> 7;              // 0..15
        float4 vx = *(const float4*)(xb + row * DDIM + k4 * 4);
        float4 vy = *(const float4*)(yb + row * DDIM + k4 * 4);
        int base = row * LDSTRU + k4 * 2;

        {   // x: hi = truncate-to-bf16 (exact as float), lo = trunc(f - hi)
            unsigned int u0 = __float_as_uint(vx.x), u1 = __float_as_uint(vx.y);
            unsigned int u2 = __float_as_uint(vx.z), u3 = __float_as_uint(vx.w);
            unsigned int h01 = (u0 >> 16) | (u1 & 0xFFFF0000u);
            unsigned int h23 = (u2 >> 16) | (u3 & 0xFFFF0000u);
            xhiW[base]     = h01;
            xhiW[base + 1] = h23;
            unsigned int l0 = __float_as_uint(vx.x - __uint_as_float(u0 & 0xFFFF0000u));
            unsigned int l1 = __float_as_uint(vx.y - __uint_as_float(u1 & 0xFFFF0000u));
            unsigned int l2 = __float_as_uint(vx.z - __uint_as_float(u2 & 0xFFFF0000u));
            unsigned int l3 = __float_as_uint(vx.w - __uint_as_float(u3 & 0xFFFF0000u));
            xloW[base]     = (l0 >> 16) | (l1 & 0xFFFF0000u);
            xloW[base + 1] = (l2 >> 16) | (l3 & 0xFFFF0000u);
        }
        {   // y: same
            unsigned int u0 = __float_as_uint(vy.x), u1 = __float_as_uint(vy.y);
            unsigned int u2 = __float_as_uint(vy.z), u3 = __float_as_uint(vy.w);
            unsigned int h01 = (u0 >> 16) | (u1 & 0xFFFF0000u);
            unsigned int h23 = (u2 >> 16) | (u3 & 0xFFFF0000u);
            yhiW[base]     = h01;
            yhiW[base + 1] = h23;
            unsigned int l0 = __float_as_uint(vy.x - __uint_as_float(u0 & 0xFFFF0000u));
            unsigned int l1 = __float_as_uint(vy.y - __uint_as_float(u1 & 0xFFFF0000u));
            unsigned int l2 = __float_as_uint(vy.z - __uint_as_float(u2 & 0xFFFF0000u));
            unsigned int l3 = __float_as_uint(vy.w - __uint_as_float(u3 & 0xFFFF0000u));
            yloW[base]     = (l0 >> 16) | (l1 & 0xFFFF0000u);
            yloW[base + 1] = (l2 >> 16) | (l3 & 0xFFFF0000u);
        }
    }
    __syncthreads();

    // ---- norms from RECONSTRUCTED hi+lo (consistent with MFMA Gram) ----
    {
        int r = tid & 127;
        const unsigned int* ph = (tid < 128 ? xhiW : yhiW) + r * LDSTRU;
        const unsigned int* pl = (tid < 128 ? xloW : yloW) + r * LDSTRU;
        float s = 0.0f;
#pragma unroll
        for (int kk = 0; kk < 32; ++kk) {
            unsigned int uh = ph[kk], ul = pl[kk];
            float e0 = __uint_as_float(uh << 16) + __uint_as_float(ul << 16);
            float e1 = __uint_as_float(uh & 0xFFFF0000u) + __uint_as_float(ul & 0xFFFF0000u);
            s = fmaf(e0, e0, s);
            s = fmaf(e1, e1, s);
        }
        if (tid < 128) xnk[r] = K2E * s; else ynk[r] = K2E * s;
    }
    __syncthreads();

    // ---- MFMA: wave w -> tile-rows {2w,2w+1} x tile-cols 0..7 (R8 order) ----
    const int wid = tid >> 6, lane = tid & 63;
    const int ln = lane & 15, q = lane >> 4;
    const unsigned short* XH = (const unsigned short*)xhiW;
    const unsigned short* XL = (const unsigned short*)xloW;
    const unsigned short* YH = (const unsigned short*)yhiW;
    const unsigned short* YL = (const unsigned short*)yloW;

#pragma unroll
    for (int tr2 = 0; tr2 < 2; ++tr2) {
        const int I0 = (wid * 2 + tr2) * 16;
        const int arow = (I0 + ln) * (2 * LDSTRU);   // ushort index of row
        short8 ah0 = *(const short8*)&XH[arow + q * 8];
        short8 ah1 = *(const short8*)&XH[arow + 32 + q * 8];
        short8 al0 = *(const short8*)&XL[arow + q * 8];
        short8 al1 = *(const short8*)&XL[arow + 32 + q * 8];

        float xnr[4];
#pragma unroll
        for (int reg = 0; reg < 4; ++reg) xnr[reg] = xnk[I0 + q * 4 + reg];

        const int Ibase = i0 + I0 + q * 4;
        float* Prow = P + (size_t)b * (MM * NN) + (size_t)(Ibase >> 3) * 4096 + (Ibase & 7) * 4;

#pragma unroll
        for (int tc = 0; tc < 8; ++tc) {
            const int J0 = tc * 16;
            const int brow = (J0 + ln) * (2 * LDSTRU);
            short8 bh0 = *(const short8*)&YH[brow + q * 8];
            short8 bh1 = *(const short8*)&YH[brow + 32 + q * 8];
            short8 bl0 = *(const short8*)&YL[brow + q * 8];
            short8 bl1 = *(const short8*)&YL[brow + 32 + q * 8];

            floatx4 acc = {0.0f, 0.0f, 0.0f, 0.0f};
            acc = __builtin_amdgcn_mfma_f32_16x16x32_bf16(ah0, bh0, acc, 0, 0, 0);
            acc = __builtin_amdgcn_mfma_f32_16x16x32_bf16(ah1, bh1, acc, 0, 0, 0);
            acc = __builtin_amdgcn_mfma_f32_16x16x32_bf16(ah0, bl0, acc, 0, 0, 0);
            acc = __builtin_amdgcn_mfma_f32_16x16x32_bf16(ah1, bl1, acc, 0, 0, 0);
            acc = __builtin_amdgcn_mfma_f32_16x16x32_bf16(al0, bh0, acc, 0, 0, 0);
            acc = __builtin_amdgcn_mfma_f32_16x16x32_bf16(al1, bh1, acc, 0, 0, 0);

            const float yn = ynk[J0 + ln];
            const int Jg = j0 + J0 + ln;
            float* Pp = Prow + (size_t)(Jg >> 2) * 32 + (Jg & 3);
#pragma unroll
            for (int reg = 0; reg < 4; ++reg) {
                float v = fmaf(acc[reg], 2.0f * K2E, -xnr[reg]) - yn;
                Pp[reg * 4] = fminf(v, 0.0f);
            }
        }
    }
}

// ---------------------------------------------------------------------------
// Kernel 2: soft-DTW DP — R8 VERBATIM (one wave/batch, lane t owns rows
// [8t,8t+8), 8x4 tiles, 191 steps, triple-buffered asm prefetch, vmcnt(8)
// scalar-tied wait, softmin via max3/med3/min3 + 2 exp2 + log2).
// FROZEN: 2-wave split, layout remap, and hard-min variants all failed.
// ---------------------------------------------------------------------------
__global__ __launch_bounds__(64, 1) void softdtw_kernel(const float* __restrict__ P,
                                                        float* __restrict__ out) {
    const int b = blockIdx.x;
    const int t = threadIdx.x;
    const float* Pb = P + (size_t)b * (MM * NN) + (size_t)t * 4096;  // t*128*32

    float4 b0[8], b1[8], b2[8];

#define LOADS(BUF, CN)                                                          \
    {                                                                           \
        int cc = (CN); cc = cc < 0 ? 0 : (cc > 127 ? 127 : cc);                 \
        const float* ap = Pb + cc * 32;                                         \
        asm volatile("global_load_dwordx4 %0, %1, off"            : "=v"(BUF[0]) : "v"(ap)); \
        asm volatile("global_load_dwordx4 %0, %1, off offset:16"  : "=v"(BUF[1]) : "v"(ap)); \
        asm volatile("global_load_dwordx4 %0, %1, off offset:32"  : "=v"(BUF[2]) : "v"(ap)); \
        asm volatile("global_load_dwordx4 %0, %1, off offset:48"  : "=v"(BUF[3]) : "v"(ap)); \
        asm volatile("global_load_dwordx4 %0, %1, off offset:64"  : "=v"(BUF[4]) : "v"(ap)); \
        asm volatile("global_load_dwordx4 %0, %1, off offset:80"  : "=v"(BUF[5]) : "v"(ap)); \
        asm volatile("global_load_dwordx4 %0, %1, off offset:96"  : "=v"(BUF[6]) : "v"(ap)); \
        asm volatile("global_load_dwordx4 %0, %1, off offset:112" : "=v"(BUF[7]) : "v"(ap)); \
    }

#define WAITCUR(CUR)                                                            \
    asm volatile("s_waitcnt vmcnt(8)"                                           \
                 : "+v"(CUR[0].x), "+v"(CUR[0].y), "+v"(CUR[0].z), "+v"(CUR[0].w), \
                   "+v"(CUR[1].x), "+v"(CUR[1].y), "+v"(CUR[1].z), "+v"(CUR[1].w), \
                   "+v"(CUR[2].x), "+v"(CUR[2].y), "+v"(CUR[2].z), "+v"(CUR[2].w), \
                   "+v"(CUR[3].x), "+v"(CUR[3].y), "+v"(CUR[3].z), "+v"(CUR[3].w), \
                   "+v"(CUR[4].x), "+v"(CUR[4].y), "+v"(CUR[4].z), "+v"(CUR[4].w), \
                   "+v"(CUR[5].x), "+v"(CUR[5].y), "+v"(CUR[5].z), "+v"(CUR[5].w), \
                   "+v"(CUR[6].x), "+v"(CUR[6].y), "+v"(CUR[6].z), "+v"(CUR[6].w), \
                   "+v"(CUR[7].x), "+v"(CUR[7].y), "+v"(CUR[7].z), "+v"(CUR[7].w));

    LOADS(b0, 0 - t)       // chunk for step 0
    LOADS(b1, 1 - t)       // chunk for step 1

    float left[8], top[4], bot[4];
#pragma unroll
    for (int r = 0; r < 8; ++r) left[r] = NEGB;
#pragma unroll
    for (int k = 0; k < 4; ++k) { top[k] = NEGB; bot[k] = NEGB; }
    float tl = (t == 0) ? 0.0f : NEGB;

#define DTW_STEP(S, CUR, FUT)                                                   \
    {                                                                           \
        WAITCUR(CUR)                                                            \
        LOADS(FUT, (S) + 2 - t)                                                 \
        const int c = (S) - t;                                                  \
        if (c >= 0 && c < 128) {                                                \
            float Rt[8][4];                                                     \
            _Pragma("unroll")                                                   \
            for (int dd = 0; dd <= 10; ++dd) {                                  \
                _Pragma("unroll")                                               \
                for (int r = 0; r < 8; ++r) {                                   \
                    const int cl = dd - r;                                      \
                    if (cl < 0 || cl > 3) continue;                             \
                    float dg, up, lf;                                           \
                    if (r == 0) { dg = (cl == 0) ? tl : top[cl - 1]; up = top[cl]; } \
                    else        { dg = (cl == 0) ? left[r - 1] : Rt[r - 1][cl - 1]; up = Rt[r - 1][cl]; } \
                    lf = (cl == 0) ? left[r] : Rt[r][cl - 1];                   \
                    float Dv = (cl == 0) ? CUR[r].x : (cl == 1) ? CUR[r].y      \
                             : (cl == 2) ? CUR[r].z : CUR[r].w;                 \
                    float mx = fmaxf(fmaxf(dg, up), lf);                        \
                    float mn = fminf(fminf(dg, up), lf);                        \
                    float md = __builtin_amdgcn_fmed3f(dg, up, lf);             \
                    float e1 = __builtin_amdgcn_exp2f(md - mx);                 \
                    float e2 = __builtin_amdgcn_exp2f(mn - mx);                 \
                    float lg = __builtin_amdgcn_logf(1.0f + e1 + e2);           \
                    Rt[r][cl] = mx + lg + Dv;                                   \
                }                                                               \
            }                                                                   \
            _Pragma("unroll")                                                   \
            for (int r = 0; r < 8; ++r) left[r] = Rt[r][3];                     \
            _Pragma("unroll")                                                   \
            for (int k = 0; k < 4; ++k) bot[k] = Rt[7][k];                      \
        }                                                                       \
        float ntl = top[3];                                                     \
        _Pragma("unroll")                                                       \
        for (int k = 0; k < 4; ++k) {                                           \
            float v = __shfl_up(bot[k], 1, 64);                                 \
            top[k] = (t == 0) ? NEGB : v;                                       \
        }                                                                       \
        tl = (t == 0) ? NEGB : ntl;                                             \
    }

    // step s: CUR = buf[s%3], FUT = buf[(s+2)%3]
    for (int p = 0; p < 63; ++p) {
        const int s = 3 * p;
        DTW_STEP(s,     b0, b2)
        DTW_STEP(s + 1, b1, b0)
        DTW_STEP(s + 2, b2, b1)
    }
    DTW_STEP(189, b0, b2)
    DTW_STEP(190, b1, b0)
#undef DTW_STEP
#undef LOADS
#undef WAITCUR

    if (t == 63) atomicAdd(out, bot[3] * (-GLN2 / 64.0f));
}

extern "C" void kernel_launch(void* const* d_in, const int* in_sizes, int n_in,
                              void* d_out, int out_size, void* d_ws, size_t ws_size,
                              hipStream_t stream) {
    const float* x = (const float*)d_in[0];   // (64, 512, 64) fp32
    const float* y = (const float*)d_in[1];   // (64, 512, 64) fp32

    float* P = (float*)d_ws;                  // 64 MB, block-linear t-domain D

    hipMemsetAsync(d_out, 0, sizeof(float), stream);
    compute_d_kernel<<<dim3(NN / 128, MM / 128, BATCH), 256, 0, stream>>>(x, y, P);
    softdtw_kernel<<<BATCH, 64, 0, stream>>>(P, (float*)d_out);
}